// Round 2
// baseline (854.094 us; speedup 1.0000x reference)
//
#include <hip/hip_runtime.h>
#include <stdint.h>

// B=8, CIN=128, COUT=256, H=256, W=256 -> pooled 128x128, out (8,256,128,128) fp32

// ---------------------------------------------------------------------------
// Kernel 0: weight prep. One block per output channel (256 blocks, 128 thr).
// Produces: packedW[oc][9][4] (bit c%32 of word c/32 = sign(w)>0),
//           corrCase[oc][9] border-correction sums, epi[oc] = {scale,b0,alpha,b1}.
// Case index = 3*hB + wB; hB: 0 none / 1 top / 2 bottom; wB: 0 none /1 left /2 right.
// ---------------------------------------------------------------------------
__global__ __launch_bounds__(128) void wprep_kernel(const float* __restrict__ w,
                                                    const float* __restrict__ pb0,
                                                    const float* __restrict__ alpha,
                                                    const float* __restrict__ pb1,
                                                    uint32_t* __restrict__ packedW,
                                                    int* __restrict__ corrCase,
                                                    float4* __restrict__ epi) {
    int oc = blockIdx.x;
    int cin = threadIdx.x;              // 0..127
    const float* wp = w + ((long)oc * 128 + cin) * 9;
    float wk[9];
    float sabs = 0.f;
#pragma unroll
    for (int k = 0; k < 9; ++k) { wk[k] = wp[k]; sabs += fabsf(wk[k]); }
    int gi = cin >> 6;                  // wave id 0/1
    int lane = cin & 63;
    __shared__ float ssum[2];
    __shared__ int spc[2][9];
    for (int off = 32; off > 0; off >>= 1) sabs += __shfl_down(sabs, off, 64);
    if (lane == 0) ssum[gi] = sabs;
#pragma unroll
    for (int k = 0; k < 9; ++k) {
        unsigned long long m = __ballot(wk[k] > 0.f);
        if (lane == 0) {
            packedW[(oc * 9 + k) * 4 + 2 * gi]     = (uint32_t)m;
            packedW[(oc * 9 + k) * 4 + 2 * gi + 1] = (uint32_t)(m >> 32);
            spc[gi][k] = __popcll(m);
        }
    }
    __syncthreads();
    if (cin == 0) {
        float s = (ssum[0] + ssum[1]) * (1.0f / 1152.0f);
        epi[oc] = make_float4(s, pb0[oc], alpha[oc], pb1[oc]);
        int ct[9];
#pragma unroll
        for (int t = 0; t < 9; ++t) ct[t] = 128 - 2 * (spc[0][t] + spc[1][t]);
        int cT = ct[0] + ct[1] + ct[2];
        int cB = ct[6] + ct[7] + ct[8];
        int cL = ct[0] + ct[3] + ct[6];
        int cR = ct[2] + ct[5] + ct[8];
        int cc[9];
        cc[0] = 0;              // interior
        cc[1] = cL;             // left
        cc[2] = cR;             // right
        cc[3] = cT;             // top
        cc[4] = cT + cL - ct[0];// top-left
        cc[5] = cT + cR - ct[2];// top-right
        cc[6] = cB;             // bottom
        cc[7] = cB + cL - ct[6];// bottom-left
        cc[8] = cB + cR - ct[8];// bottom-right
#pragma unroll
        for (int k = 0; k < 9; ++k) corrCase[oc * 9 + k] = cc[k];
    }
}

// ---------------------------------------------------------------------------
// Kernel 1: avgpool 2x2 + bias + sign -> channel-bit-packed activations.
// Grid (128 h, 8 b), 256 threads. packedA[b][h][w][4] u32, bit i of word q =
// (pooled[c=32q+i] + bias > 0).
// ---------------------------------------------------------------------------
__global__ __launch_bounds__(256) void pool_pack_kernel(const float* __restrict__ x,
                                                        const float* __restrict__ bias,
                                                        uint32_t* __restrict__ packedA) {
    int h = blockIdx.x;    // pooled row 0..127
    int b = blockIdx.y;    // 0..7
    int tid = threadIdx.x;
    __shared__ float sbias[128];
    __shared__ uint8_t sb[128 * 132];   // [c][w] bytes, row stride 132
    if (tid < 128) sbias[tid] = bias[tid];
    __syncthreads();
    const float4* x4 = reinterpret_cast<const float4*>(x);
#pragma unroll 4
    for (int it = 0; it < 32; ++it) {
        int j = it * 256 + tid;         // [0, 8192)
        int c = j >> 6;                 // 0..127
        int wq = j & 63;                // float4 col -> output pixels 2wq, 2wq+1
        long base = ((long)(b * 128 + c) * 256 + 2 * h) * 64 + wq;
        float4 f0 = x4[base];
        float4 f1 = x4[base + 64];
        float p0 = (f0.x + f0.y + f1.x + f1.y) * 0.25f + sbias[c];
        float p1 = (f0.z + f0.w + f1.z + f1.w) * 0.25f + sbias[c];
        uint16_t v = (uint16_t)((p0 > 0.f ? 1u : 0u) | ((p1 > 0.f ? 1u : 0u) << 8));
        *reinterpret_cast<uint16_t*>(&sb[c * 132 + 2 * wq]) = v;
    }
    __syncthreads();
#pragma unroll
    for (int it = 0; it < 2; ++it) {
        int idx = it * 256 + tid;       // [0,512)
        int q = idx & 3;
        int w = idx >> 2;
        uint32_t word = 0;
#pragma unroll
        for (int i = 0; i < 32; ++i)
            word |= ((uint32_t)sb[(32 * q + i) * 132 + w]) << i;
        packedA[(((long)b * 128 + h) * 128 + w) * 4 + q] = word;
    }
}

// ---------------------------------------------------------------------------
// Kernel 2: XNOR-popcount 3x3 conv + RPReLU.
// Grid (64 hpair, 2 oc-half, 8 b), 256 thr = 4 waves; wave handles 32 oc.
// Lane owns a 2x2 pixel patch (rows 2hp,2hp+1; cols 2l,2l+1): act footprint
// 4x4 uint4 = 64 VGPRs, register-resident across the oc loop.
// ---------------------------------------------------------------------------
__device__ __forceinline__ int popc4(uint4 a, uint4 w) {
    return __builtin_popcount(a.x ^ w.x) + __builtin_popcount(a.y ^ w.y) +
           __builtin_popcount(a.z ^ w.z) + __builtin_popcount(a.w ^ w.w);
}

__global__ __launch_bounds__(256, 4) void conv_kernel(const uint32_t* __restrict__ packedA,
                                                      const uint32_t* __restrict__ packedW,
                                                      const int* __restrict__ corrCase,
                                                      const float4* __restrict__ epi,
                                                      float* __restrict__ out) {
    int hp  = blockIdx.x;        // 0..63 -> rows 2hp, 2hp+1
    int och = blockIdx.y;        // 0..1  -> oc base 128*och
    int b   = blockIdx.z;
    int tid = threadIdx.x;
    int ocbase = och * 128;

    __shared__ uint4 wlds[128 * 9];     // 18432 B
    __shared__ uint4 alds[4][132];      //  8448 B  rows 2hp-1..2hp+2, col idx = w+1
    __shared__ int   clds[128 * 9];     //  4608 B
    __shared__ float4 elds[128];        //  2048 B

    const uint4* pw4 = reinterpret_cast<const uint4*>(packedW);
    for (int i = tid; i < 128 * 9; i += 256) wlds[i] = pw4[ocbase * 9 + i];
    const uint4* pa4 = reinterpret_cast<const uint4*>(packedA);
    for (int i = tid; i < 4 * 132; i += 256) {
        int r = i / 132, c = i % 132;
        int hh = 2 * hp - 1 + r;
        int col = c - 1;
        uint4 v = make_uint4(0u, 0u, 0u, 0u);
        if (col >= 0 && col < 128 && hh >= 0 && hh < 128)
            v = pa4[((b * 128 + hh) << 7) + col];
        alds[r][c] = v;
    }
    for (int i = tid; i < 128 * 9; i += 256) clds[i] = corrCase[ocbase * 9 + i];
    if (tid < 128) elds[tid] = epi[ocbase + tid];
    __syncthreads();

    int wv = tid >> 6, lane = tid & 63;
    int w0 = 2 * lane;                  // output cols w0, w0+1
    uint4 A[4][4];                      // [row 2hp-1+rr][col w0-1+cc]
#pragma unroll
    for (int rr = 0; rr < 4; ++rr)
#pragma unroll
        for (int cc = 0; cc < 4; ++cc)
            A[rr][cc] = alds[rr][w0 + cc];
    __builtin_amdgcn_sched_barrier(0);  // keep act regs out of the oc loop

    int r0 = 2 * hp, r1 = r0 + 1;
    int hB0 = (r0 == 0)   ? 3 : 0;      // pre-multiplied by 3
    int hB1 = (r1 == 127) ? 6 : 0;
    int wBl = (lane == 0)  ? 1 : 0;
    int wBr = (lane == 63) ? 2 : 0;
    int c00 = hB0 + wBl, c01 = hB0 + wBr;
    int c10 = hB1 + wBl, c11 = hB1 + wBr;

    for (int i = 0; i < 32; ++i) {
        int ocl = wv * 32 + i;          // wave-uniform
        const uint4* wp = &wlds[ocl * 9];
        int a00 = 0, a01 = 0, a10 = 0, a11 = 0;
#pragma unroll
        for (int r = 0; r < 3; ++r)
#pragma unroll
            for (int d = 0; d < 3; ++d) {
                uint4 wt = wp[r * 3 + d];
                a00 += popc4(A[r][d],         wt);
                a01 += popc4(A[r][d + 1],     wt);
                a10 += popc4(A[r + 1][d],     wt);
                a11 += popc4(A[r + 1][d + 1], wt);
            }
        int cb = ocl * 9;
        int t00 = 1152 - 2 * a00 - clds[cb + c00];
        int t01 = 1152 - 2 * a01 - clds[cb + c01];
        int t10 = 1152 - 2 * a10 - clds[cb + c10];
        int t11 = 1152 - 2 * a11 - clds[cb + c11];
        float4 e = elds[ocl];
        float y00 = e.x * (float)t00 + e.y; y00 = (y00 >= 0.f) ? y00 : e.z * y00; y00 += e.w;
        float y01 = e.x * (float)t01 + e.y; y01 = (y01 >= 0.f) ? y01 : e.z * y01; y01 += e.w;
        float y10 = e.x * (float)t10 + e.y; y10 = (y10 >= 0.f) ? y10 : e.z * y10; y10 += e.w;
        float y11 = e.x * (float)t11 + e.y; y11 = (y11 >= 0.f) ? y11 : e.z * y11; y11 += e.w;
        long ob = (((long)(b * 256 + ocbase + ocl) * 128 + r0) << 7) + w0;
        *reinterpret_cast<float2*>(out + ob)       = make_float2(y00, y01);
        *reinterpret_cast<float2*>(out + ob + 128) = make_float2(y10, y11);
    }
}

// ---------------------------------------------------------------------------
extern "C" void kernel_launch(void* const* d_in, const int* in_sizes, int n_in,
                              void* d_out, int out_size, void* d_ws, size_t ws_size,
                              hipStream_t stream) {
    const float* x          = (const float*)d_in[0];  // (8,128,256,256)
    const float* weight     = (const float*)d_in[1];  // (256,128,3,3)
    const float* move0_bias = (const float*)d_in[2];  // 128
    const float* pb0        = (const float*)d_in[3];  // 256
    const float* alpha      = (const float*)d_in[4];  // 256
    const float* pb1        = (const float*)d_in[5];  // 256
    float* out = (float*)d_out;

    char* ws = (char*)d_ws;
    uint32_t* packedA  = (uint32_t*)ws;                          // 2,097,152 B
    uint32_t* packedW  = (uint32_t*)(ws + 2097152);              //    36,864 B
    int*      corrCase = (int*)     (ws + 2097152 + 36864);      //     9,216 B
    float4*   epi      = (float4*)  (ws + 2097152 + 36864 + 9216); //   4,096 B

    wprep_kernel<<<256, 128, 0, stream>>>(weight, pb0, alpha, pb1,
                                          packedW, corrCase, epi);
    pool_pack_kernel<<<dim3(128, 8), 256, 0, stream>>>(x, move0_bias, packedA);
    conv_kernel<<<dim3(64, 2, 8), 256, 0, stream>>>(packedA, packedW, corrCase, epi, out);
}

// Round 3
// 509.991 us; speedup vs baseline: 1.6747x; 1.6747x over previous
//
#include <hip/hip_runtime.h>
#include <stdint.h>

// B=8, CIN=128, COUT=256, H=256, W=256 -> pooled 128x128, out (8,256,128,128) fp32

// Per-oc packed record in ocdata, stride 56 u32 (224 B):
//   [0..35]  packed weight bits: word (t*4+q) = bits of cin 32q..32q+31, tap t
//   [36..44] border corr (as int): case 3*hB+wB; hB 0/1(top)/2(bot), wB 0/1(L)/2(R)
//   [48]     scale, [49] pr_bias0, [50] alpha, [51] pr_bias1  (floats)

// ---------------------------------------------------------------------------
// Kernel 0: weight prep. One block per output channel (256 blocks, 128 thr).
// ---------------------------------------------------------------------------
__global__ __launch_bounds__(128) void wprep_kernel(const float* __restrict__ w,
                                                    const float* __restrict__ pb0,
                                                    const float* __restrict__ alpha,
                                                    const float* __restrict__ pb1,
                                                    uint32_t* __restrict__ ocdata) {
    int oc = blockIdx.x;
    int cin = threadIdx.x;              // 0..127
    const float* wp = w + ((long)oc * 128 + cin) * 9;
    float wk[9];
    float sabs = 0.f;
#pragma unroll
    for (int k = 0; k < 9; ++k) { wk[k] = wp[k]; sabs += fabsf(wk[k]); }
    int gi = cin >> 6;                  // wave id 0/1
    int lane = cin & 63;
    __shared__ float ssum[2];
    __shared__ int spc[2][9];
    for (int off = 32; off > 0; off >>= 1) sabs += __shfl_down(sabs, off, 64);
    if (lane == 0) ssum[gi] = sabs;
    uint32_t* od = ocdata + (size_t)oc * 56;
#pragma unroll
    for (int k = 0; k < 9; ++k) {
        unsigned long long m = __ballot(wk[k] > 0.f);
        if (lane == 0) {
            od[k * 4 + 2 * gi]     = (uint32_t)m;
            od[k * 4 + 2 * gi + 1] = (uint32_t)(m >> 32);
            spc[gi][k] = __popcll(m);
        }
    }
    __syncthreads();
    if (cin == 0) {
        float s = (ssum[0] + ssum[1]) * (1.0f / 1152.0f);
        od[48] = __float_as_uint(s);
        od[49] = __float_as_uint(pb0[oc]);
        od[50] = __float_as_uint(alpha[oc]);
        od[51] = __float_as_uint(pb1[oc]);
        int ct[9];
#pragma unroll
        for (int t = 0; t < 9; ++t) ct[t] = 128 - 2 * (spc[0][t] + spc[1][t]);
        int cT = ct[0] + ct[1] + ct[2];
        int cB = ct[6] + ct[7] + ct[8];
        int cL = ct[0] + ct[3] + ct[6];
        int cR = ct[2] + ct[5] + ct[8];
        od[36 + 0] = (uint32_t)0;                       // interior
        od[36 + 1] = (uint32_t)cL;                      // left
        od[36 + 2] = (uint32_t)cR;                      // right
        od[36 + 3] = (uint32_t)cT;                      // top
        od[36 + 4] = (uint32_t)(cT + cL - ct[0]);       // top-left
        od[36 + 5] = (uint32_t)(cT + cR - ct[2]);       // top-right
        od[36 + 6] = (uint32_t)cB;                      // bottom
        od[36 + 7] = (uint32_t)(cB + cL - ct[6]);       // bottom-left
        od[36 + 8] = (uint32_t)(cB + cR - ct[8]);       // bottom-right
        od[45] = od[46] = od[47] = 0u;
        od[52] = od[53] = od[54] = od[55] = 0u;
    }
}

// ---------------------------------------------------------------------------
// Kernel 1: avgpool 2x2 + bias + sign -> channel-bit-packed activations.
// Grid (128 h, 8 b), 256 threads. packedA[b][h][w][4] u32, bit i of word q =
// (pooled[c=32q+i] + bias > 0).
// ---------------------------------------------------------------------------
__global__ __launch_bounds__(256) void pool_pack_kernel(const float* __restrict__ x,
                                                        const float* __restrict__ bias,
                                                        uint32_t* __restrict__ packedA) {
    int h = blockIdx.x;    // pooled row 0..127
    int b = blockIdx.y;    // 0..7
    int tid = threadIdx.x;
    __shared__ float sbias[128];
    __shared__ uint8_t sb[128 * 132];   // [c][w] bytes, row stride 132
    if (tid < 128) sbias[tid] = bias[tid];
    __syncthreads();
    const float4* x4 = reinterpret_cast<const float4*>(x);
#pragma unroll 4
    for (int it = 0; it < 32; ++it) {
        int j = it * 256 + tid;         // [0, 8192)
        int c = j >> 6;                 // 0..127
        int wq = j & 63;                // float4 col -> output pixels 2wq, 2wq+1
        long base = ((long)(b * 128 + c) * 256 + 2 * h) * 64 + wq;
        float4 f0 = x4[base];
        float4 f1 = x4[base + 64];
        float p0 = (f0.x + f0.y + f1.x + f1.y) * 0.25f + sbias[c];
        float p1 = (f0.z + f0.w + f1.z + f1.w) * 0.25f + sbias[c];
        uint16_t v = (uint16_t)((p0 > 0.f ? 1u : 0u) | ((p1 > 0.f ? 1u : 0u) << 8));
        *reinterpret_cast<uint16_t*>(&sb[c * 132 + 2 * wq]) = v;
    }
    __syncthreads();
#pragma unroll
    for (int it = 0; it < 2; ++it) {
        int idx = it * 256 + tid;       // [0,512)
        int q = idx & 3;
        int w = idx >> 2;
        uint32_t word = 0;
#pragma unroll
        for (int i = 0; i < 32; ++i)
            word |= ((uint32_t)sb[(32 * q + i) * 132 + w]) << i;
        packedA[(((long)b * 128 + h) * 128 + w) * 4 + q] = word;
    }
}

// ---------------------------------------------------------------------------
// Kernel 2: XNOR-popcount 3x3 conv + RPReLU.
// Grid (64 hpair, 2 oc-half, 8 b), 256 thr = 4 waves.
// Wave wv: row = 2*hp + (wv>>1), cols 64*(wv&1)..+63; lane = one pixel.
// Act window: 9 uint4 = 36 VGPRs, pinned with opaque asm so the compiler
// cannot sink the LDS reads into the oc loop (round-1 failure) and has no
// big array to spill (round-2 failure). Weights/corr/epi are wave-uniform
// loads from ocdata (s_load / L1-resident broadcast).
// ---------------------------------------------------------------------------
#define PIN4(v) asm volatile("" : "+v"(v.x), "+v"(v.y), "+v"(v.z), "+v"(v.w))

__global__ __launch_bounds__(256, 4) void conv_kernel(const uint32_t* __restrict__ packedA,
                                                      const uint32_t* __restrict__ ocdata,
                                                      float* __restrict__ out) {
    int hp  = blockIdx.x;        // 0..63
    int och = blockIdx.y;        // 0..1
    int b   = blockIdx.z;
    int tid = threadIdx.x;

    __shared__ uint4 alds[4][132];      // rows 2hp-1..2hp+2, col idx = w+1
    const uint4* pa4 = reinterpret_cast<const uint4*>(packedA);
    for (int i = tid; i < 4 * 132; i += 256) {
        int r = i / 132, c = i % 132;
        int hh = 2 * hp - 1 + r;
        int col = c - 1;
        uint4 v = make_uint4(0u, 0u, 0u, 0u);
        if (col >= 0 && col < 128 && hh >= 0 && hh < 128)
            v = pa4[((b * 128 + hh) << 7) + col];
        alds[r][c] = v;
    }
    __syncthreads();

    int wv = tid >> 6, lane = tid & 63;
    int lr = wv >> 1;                   // 0/1 -> which output row
    int cg = wv & 1;                    // 0/1 -> col group
    int row = 2 * hp + lr;
    int col = (cg << 6) + lane;

    uint4 A0 = alds[lr + 0][col + 0], A1 = alds[lr + 0][col + 1], A2 = alds[lr + 0][col + 2];
    uint4 A3 = alds[lr + 1][col + 0], A4 = alds[lr + 1][col + 1], A5 = alds[lr + 1][col + 2];
    uint4 A6 = alds[lr + 2][col + 0], A7 = alds[lr + 2][col + 1], A8 = alds[lr + 2][col + 2];
    PIN4(A0); PIN4(A1); PIN4(A2); PIN4(A3); PIN4(A4);
    PIN4(A5); PIN4(A6); PIN4(A7); PIN4(A8);

    int hB3 = (row == 0) ? 3 : ((row == 127) ? 6 : 0);
    bool bl = (col == 0);
    bool br = (col == 127);

    int ocbase = och << 7;
    long obase = (((long)(b * 256 + ocbase) * 128 + row) << 7) + col;
    const uint32_t* od = ocdata + (size_t)ocbase * 56;

    for (int i = 0; i < 128; ++i, od += 56, obase += 16384) {
        const uint4* wt = reinterpret_cast<const uint4*>(od);
        uint4 w0 = wt[0], w1 = wt[1], w2 = wt[2], w3 = wt[3], w4 = wt[4];
        uint4 w5 = wt[5], w6 = wt[6], w7 = wt[7], w8 = wt[8];
        int acc = 0;
        acc += __builtin_popcount(A0.x ^ w0.x) + __builtin_popcount(A0.y ^ w0.y)
             + __builtin_popcount(A0.z ^ w0.z) + __builtin_popcount(A0.w ^ w0.w);
        acc += __builtin_popcount(A1.x ^ w1.x) + __builtin_popcount(A1.y ^ w1.y)
             + __builtin_popcount(A1.z ^ w1.z) + __builtin_popcount(A1.w ^ w1.w);
        acc += __builtin_popcount(A2.x ^ w2.x) + __builtin_popcount(A2.y ^ w2.y)
             + __builtin_popcount(A2.z ^ w2.z) + __builtin_popcount(A2.w ^ w2.w);
        acc += __builtin_popcount(A3.x ^ w3.x) + __builtin_popcount(A3.y ^ w3.y)
             + __builtin_popcount(A3.z ^ w3.z) + __builtin_popcount(A3.w ^ w3.w);
        acc += __builtin_popcount(A4.x ^ w4.x) + __builtin_popcount(A4.y ^ w4.y)
             + __builtin_popcount(A4.z ^ w4.z) + __builtin_popcount(A4.w ^ w4.w);
        acc += __builtin_popcount(A5.x ^ w5.x) + __builtin_popcount(A5.y ^ w5.y)
             + __builtin_popcount(A5.z ^ w5.z) + __builtin_popcount(A5.w ^ w5.w);
        acc += __builtin_popcount(A6.x ^ w6.x) + __builtin_popcount(A6.y ^ w6.y)
             + __builtin_popcount(A6.z ^ w6.z) + __builtin_popcount(A6.w ^ w6.w);
        acc += __builtin_popcount(A7.x ^ w7.x) + __builtin_popcount(A7.y ^ w7.y)
             + __builtin_popcount(A7.z ^ w7.z) + __builtin_popcount(A7.w ^ w7.w);
        acc += __builtin_popcount(A8.x ^ w8.x) + __builtin_popcount(A8.y ^ w8.y)
             + __builtin_popcount(A8.z ^ w8.z) + __builtin_popcount(A8.w ^ w8.w);

        int c0 = (int)od[36 + hB3];
        int cL = (int)od[37 + hB3];
        int cR = (int)od[38 + hB3];
        int corr = bl ? cL : (br ? cR : c0);
        int tsum = 1152 - 2 * acc - corr;

        float s  = __uint_as_float(od[48]);
        float b0 = __uint_as_float(od[49]);
        float al = __uint_as_float(od[50]);
        float b1 = __uint_as_float(od[51]);
        float y = fmaf((float)tsum, s, b0);
        y = (y >= 0.f) ? y : al * y;
        out[obase] = y + b1;
    }
}

// ---------------------------------------------------------------------------
extern "C" void kernel_launch(void* const* d_in, const int* in_sizes, int n_in,
                              void* d_out, int out_size, void* d_ws, size_t ws_size,
                              hipStream_t stream) {
    const float* x          = (const float*)d_in[0];  // (8,128,256,256)
    const float* weight     = (const float*)d_in[1];  // (256,128,3,3)
    const float* move0_bias = (const float*)d_in[2];  // 128
    const float* pb0        = (const float*)d_in[3];  // 256
    const float* alpha      = (const float*)d_in[4];  // 256
    const float* pb1        = (const float*)d_in[5];  // 256
    float* out = (float*)d_out;

    char* ws = (char*)d_ws;
    uint32_t* packedA = (uint32_t*)ws;                 // 2,097,152 B
    uint32_t* ocdata  = (uint32_t*)(ws + 2097152);     //    57,344 B

    wprep_kernel<<<256, 128, 0, stream>>>(weight, pb0, alpha, pb1, ocdata);
    pool_pack_kernel<<<dim3(128, 8), 256, 0, stream>>>(x, move0_bias, packedA);
    conv_kernel<<<dim3(64, 2, 8), 256, 0, stream>>>(packedA, ocdata, out);
}